// Round 3
// baseline (154.018 us; speedup 1.0000x reference)
//
#include <hip/hip_runtime.h>
#include <math.h>

#define N 4096
#define D 512
#define TOPK 10
#define TOPK_HALF 5
#define NT 32
#define TRI_BLOCKS (NT * (NT + 1) / 2)   // 528
#define WC_BLOCKS (N * TOPK_HALF / 16)   // 1280: one 16-lane group per task
#define INV_N (1.0f / 4096.0f)
#define TPAD 132                          // transpose-tile pad: 2*TPAD%32==8 -> conflict-free

typedef __bf16 bf16;
typedef __bf16 bf16x4 __attribute__((ext_vector_type(4)));
typedef __bf16 bf16x8 __attribute__((ext_vector_type(8)));
typedef float f32x4 __attribute__((ext_vector_type(4)));
typedef _Float16 f16;
typedef _Float16 f16x4 __attribute__((ext_vector_type(4)));
typedef _Float16 f16x8 __attribute__((ext_vector_type(8)));
typedef unsigned short u16;
typedef unsigned short u16x8 __attribute__((ext_vector_type(8)));
typedef unsigned int u32;

__device__ __forceinline__ void gl_lds16(const void* g, void* l) {
  __builtin_amdgcn_global_load_lds(
      (const __attribute__((address_space(1))) void*)g,
      (__attribute__((address_space(3))) void*)l, 16, 0, 0);
}

__device__ __forceinline__ float f16tof(u16 h) {
  return (float)__builtin_bit_cast(_Float16, h);
}

// ---------------- K0: L2-normalize both matrices (2 rows/block, float4 loads) ----------------
__global__ __launch_bounds__(256) void k_normalize2(const float* __restrict__ xs,
                                                    const float* __restrict__ xt,
                                                    bf16* __restrict__ ys,
                                                    bf16* __restrict__ yt,
                                                    float* __restrict__ rsq_s,
                                                    float* __restrict__ rsq_t,
                                                    float* __restrict__ rowsum) {
  int b = blockIdx.x;                 // handles combined rows 2b, 2b+1 (of 8192)
  int tid = threadIdx.x;
  int half = tid >> 7;                // which row of the pair
  int l = tid & 127;                  // lane within row: 4 floats each
  int row2 = 2 * b + half;
  int is_t = row2 >> 12;
  int row = row2 & (N - 1);
  const float* x = is_t ? xt : xs;
  bf16* y = is_t ? yt : ys;
  float* rowsq = is_t ? rsq_t : rsq_s;
  const float* xr = x + (size_t)row * D;
  float4 v = *(const float4*)(xr + l * 4);
  float ss = v.x * v.x + v.y * v.y + v.z * v.z + v.w * v.w;
  __shared__ float red[4];
  __shared__ float red2[4];
  for (int off = 32; off > 0; off >>= 1) ss += __shfl_down(ss, off, 64);
  if ((tid & 63) == 0) red[tid >> 6] = ss;
  __syncthreads();
  float tot = red[half * 2] + red[half * 2 + 1];
  float inv = 1.0f / fmaxf(sqrtf(tot), 1e-12f);
  bf16x4 bv;
  bv[0] = (bf16)(v.x * inv); bv[1] = (bf16)(v.y * inv);
  bv[2] = (bf16)(v.z * inv); bv[3] = (bf16)(v.w * inv);
  *(bf16x4*)(y + (size_t)row * D + l * 4) = bv;
  float f0 = (float)bv[0], f1 = (float)bv[1], f2 = (float)bv[2], f3 = (float)bv[3];
  float s2 = f0 * f0 + f1 * f1 + f2 * f2 + f3 * f3;
  for (int off = 32; off > 0; off >>= 1) s2 += __shfl_down(s2, off, 64);
  if ((tid & 63) == 0) red2[tid >> 6] = s2;
  __syncthreads();
  if ((tid & 127) == 0) {
    rowsq[row] = red2[half * 2] + red2[half * 2 + 1];
    if (!is_t) rowsum[row] = 0.f;
  }
}

// ---------------- Gram: m97-structure BK=64 single-buffer K-loop,
//                  bank-conflict-free via pre-swizzled global source ----------------
// LDS slot map (per 128x64 bf16 panel, 1024 slots of 16B): slot s holds
// row r = s>>3, chunk cs = (s&7) ^ (r&7).  Read of (r, cs) uses
// addr = r*128 + ((cs ^ (r&7)) * 16  -> bank base 4*(cs^(r&7)) spreads the
// 16 row-lanes of a ds_read_b128 across all 8 bases (2-way = free).
__global__ __launch_bounds__(256) void k_dgram3(const bf16* __restrict__ S,
                                                const bf16* __restrict__ T,
                                                const float* __restrict__ rsq_s,
                                                const float* __restrict__ rsq_t,
                                                f16* __restrict__ Gsd,
                                                f16* __restrict__ Gwp,
                                                float* __restrict__ rowsum) {
  __shared__ __align__(16) char sm[33792];  // J[0,16K) I[16K,32K) / [128][TPAD] f16 transpose union
  f16* tp = (f16*)sm;

  int z = blockIdx.y;
  const bf16* Y = z ? T : S;
  const float* rsq = z ? rsq_t : rsq_s;
  f16* G = z ? Gwp : Gsd;

  // XCD-chunked swizzle (bijective: 528 % 8 == 0)
  int orig = blockIdx.x;
  int t = (orig & 7) * (TRI_BLOCKS / 8) + (orig >> 3);
  int by = 0;
  while (t >= NT - by) { t -= NT - by; ++by; }
  int bx = by + t;
  bool offdiag = (bx != by);

  int tid = threadIdx.x;
  int lane = tid & 63, w = tid >> 6;
  int wr = w >> 1, wc = w & 1;
  int quad = lane >> 4, c = lane & 15;

  const char* Jbase = (const char*)(Y + (size_t)(bx * 128) * D);
  const char* Ibase = (const char*)(Y + (size_t)(by * 128) * D);

  // staging: 4 issues per panel per thread; issue i covers slot s = i*256+tid
  int goff[4];
  int ldso[4];
#pragma unroll
  for (int i = 0; i < 4; ++i) {
    int s = i * 256 + tid;
    int r = s >> 3;
    int cs = (tid & 7) ^ (r & 7);
    goff[i] = r * (D * 2) + cs * 16;
    ldso[i] = (i * 256 + w * 64) * 16;   // wave-uniform base; HW adds lane*16
  }

  int jrow = wr * 64 + c;
  int irow = wc * 64 + c;
  int x7 = c & 7;
  int csx0 = ((quad) ^ x7) * 16;         // chunk m=0: cs = quad
  int csx1 = ((4 + quad) ^ x7) * 16;     // chunk m=1: cs = 4+quad

  f32x4 acc[4][4] = {};
  for (int tt = 0; tt < 8; ++tt) {
    int kb = tt * 128;                   // byte offset of this BK=64 K-slab
#pragma unroll
    for (int i = 0; i < 4; ++i) gl_lds16(Jbase + goff[i] + kb, sm + ldso[i]);
#pragma unroll
    for (int i = 0; i < 4; ++i) gl_lds16(Ibase + goff[i] + kb, sm + 16384 + ldso[i]);
    asm volatile("s_waitcnt vmcnt(0)\n\ts_barrier" ::: "memory");
    {
      const char* Jc = sm;
      const char* Ic = sm + 16384;
#pragma unroll
      for (int m = 0; m < 2; ++m) {
        int csx = m ? csx1 : csx0;
        bf16x8 af[4], bfr[4];
#pragma unroll
        for (int u = 0; u < 4; ++u)
          af[u] = *(const bf16x8*)(Jc + jrow * 128 + u * 2048 + csx);
#pragma unroll
        for (int v = 0; v < 4; ++v)
          bfr[v] = *(const bf16x8*)(Ic + irow * 128 + v * 2048 + csx);
#pragma unroll
        for (int u = 0; u < 4; ++u)
#pragma unroll
          for (int v = 0; v < 4; ++v)
            acc[u][v] = __builtin_amdgcn_mfma_f32_16x16x32_bf16(
                af[u], bfr[v], acc[u][v], 0, 0, 0);
      }
    }
    // own-wave ds_reads complete (rule #18: MFMA may sink past a bare barrier)
    asm volatile("s_waitcnt lgkmcnt(0)\n\ts_barrier" ::: "memory");
  }
  // staging buffers dead; tp union safe (all waves past lgkmcnt(0)+barrier)

  // direct store G[i][j] (+ transpose-tile write for off-diag)
#pragma unroll
  for (int v = 0; v < 4; ++v) {
    int il = wc * 64 + v * 16 + c;
    int ig = by * 128 + il;
    float ri = rsq[ig];
    float rsv = 0.f;
#pragma unroll
    for (int u = 0; u < 4; ++u) {
      int jl0 = wr * 64 + u * 16 + quad * 4;
      int jb0i = bx * 128 + jl0;
      float4 rj = *(const float4*)(rsq + jb0i);
      const float* rjp = (const float*)&rj;
      f32x4 a = acc[u][v];
      f16x4 st;
      if (z == 0) {
#pragma unroll
        for (int reg = 0; reg < 4; ++reg) {
          float sq = fmaxf(ri + rjp[reg] - 2.0f * a[reg], 0.0f);
          float val = __builtin_amdgcn_sqrtf(sq);   // 1 x v_sqrt_f32; f16-stored
          st[reg] = (_Float16)val;
          rsv += val;
        }
      } else {
#pragma unroll
        for (int reg = 0; reg < 4; ++reg) {
          float sq = fmaxf(ri + rjp[reg] - 2.0f * a[reg], 0.0f);
          st[reg] = (_Float16)__expf(-sq);          // v_exp-based; f16-stored
        }
      }
      *(f16x4*)(G + (size_t)ig * N + jb0i) = st;
      if (offdiag) {
#pragma unroll
        for (int reg = 0; reg < 4; ++reg) tp[(jl0 + reg) * TPAD + il] = st[reg];
      }
    }
    if (z == 0) {
      rsv += __shfl_xor(rsv, 16, 64);
      rsv += __shfl_xor(rsv, 32, 64);
      if (lane < 16) atomicAdd(&rowsum[ig], rsv);
    }
  }

  // mirrored store G[j][i]: 16 lanes/row, 256 B contiguous -> full-line writes
  if (offdiag) {
    __syncthreads();
    int rloc = tid >> 4;
    int cseg = tid & 15;
#pragma unroll
    for (int it = 0; it < 8; ++it) {
      int jl = it * 16 + rloc;
      int jg = bx * 128 + jl;
      f16x8 v8 = *(f16x8*)&tp[jl * TPAD + cseg * 8];
      *(f16x8*)(G + (size_t)jg * N + by * 128 + cseg * 8) = v8;
      if (z == 0) {
        float csum = 0.f;
#pragma unroll
        for (int e = 0; e < 8; ++e) csum += (float)v8[e];
        csum += __shfl_xor(csum, 1, 64);
        csum += __shfl_xor(csum, 2, 64);
        csum += __shfl_xor(csum, 4, 64);
        csum += __shfl_xor(csum, 8, 64);
        if (cseg == 0) atomicAdd(&rowsum[jg], csum);
      }
    }
  }
}

// ---------------- Row pass: bitonic top-10 + dense loss; register merge-path tree ----------------
__global__ __launch_bounds__(256) void k_rowpass(const f16* __restrict__ Gs,
                                                 const f16* __restrict__ Gw,
                                                 const int* __restrict__ ids,
                                                 const float* __restrict__ rowsum,
                                                 int* __restrict__ topk,
                                                 double* __restrict__ pd) {
  __shared__ u32 lds[256 * TOPK];  // 10 KB
  __shared__ double dred[4];
  int i = blockIdx.x, tid = threadIdx.x;
  int idi = ids[i];
  float invm = 1.0f / (rowsum[i] * INV_N);
  const u16* srow = (const u16*)(Gs + (size_t)i * N);
  const u16* wrow = (const u16*)(Gw + (size_t)i * N);
  u32 key[16];
  float dsum = 0.f;
  int j0 = tid * 16;
#pragma unroll
  for (int h = 0; h < 2; ++h) {
    int jb = j0 + h * 8;
    u16x8 sv = *(const u16x8*)(srow + jb);
    u16x8 wv = *(const u16x8*)(wrow + jb);
    int4 id0 = *(const int4*)(ids + jb);
    int4 id1 = *(const int4*)(ids + jb + 4);
    const int* idp = (const int*)&id0;
    const int* idp1 = (const int*)&id1;
#pragma unroll
    for (int e = 0; e < 8; ++e) {
      int j = jb + e;
      u16 hw = wv[e];
      float wp = f16tof(hw);
      if (j != i) {
        float sdn = f16tof(sv[e]) * invm;
        float r = fmaxf(1.0f - sdn, 0.0f); r *= r;
        dsum += r + 0.5f * wp * (sdn * sdn - r);
      }
      int idj = (e < 4) ? idp[e] : idp1[e - 4];
      u16 hk = (idj == idi) ? (u16)0x3C00 : hw;
      key[h * 8 + e] = ((u32)hk << 16) | (u32)(4095 - j);
    }
  }
  // bitonic sort-16 descending (branch-free)
#pragma unroll
  for (int kk = 2; kk <= 16; kk <<= 1) {
#pragma unroll
    for (int jj = kk >> 1; jj > 0; jj >>= 1) {
#pragma unroll
      for (int ii = 0; ii < 16; ++ii) {
        int ll = ii ^ jj;
        if (ll > ii) {
          bool desc = ((ii & kk) == 0);
          u32 a = key[ii], b = key[ll];
          bool sw = desc ? (a < b) : (a > b);
          key[ii] = sw ? b : a;
          key[ll] = sw ? a : b;
        }
      }
    }
  }
  double dl = (double)dsum;
  for (int off = 32; off > 0; off >>= 1) dl += __shfl_down(dl, off, 64);
  if ((tid & 63) == 0) dred[tid >> 6] = dl;
#pragma unroll
  for (int o = 0; o < TOPK; ++o) lds[tid * TOPK + o] = key[o];
  __syncthreads();
  // merge tree: load both lists, merge-path in registers (no dependent LDS chains)
  for (int off = 128; off >= 1; off >>= 1) {
    if (tid < off) {
      u32 A[TOPK], B[TOPK];
#pragma unroll
      for (int o = 0; o < TOPK; ++o) {
        A[o] = lds[tid * TOPK + o];
        B[o] = lds[(tid + off) * TOPK + o];
      }
      u32 out[TOPK];
#pragma unroll
      for (int o = 0; o < TOPK; ++o) {
        u32 m = A[o] > B[o] ? A[o] : B[o];
#pragma unroll
        for (int p = 0; p < o; ++p) {
          u32 mn = A[p] < B[o - 1 - p] ? A[p] : B[o - 1 - p];
          m = m > mn ? m : mn;
        }
        out[o] = m;
      }
#pragma unroll
      for (int o = 0; o < TOPK; ++o) lds[tid * TOPK + o] = out[o];
    }
    __syncthreads();
  }
  if (tid == 0) {
#pragma unroll
    for (int o = 0; o < TOPK; ++o)
      topk[i * TOPK + o] = 4095 - (int)(lds[o] & 0xFFFu);
    pd[i] = dred[0] + dred[1] + dred[2] + dred[3];
  }
}

// ---------------- mutual-kNN lists: one 16-lane group per row, ballot-compaction ----------------
__global__ __launch_bounds__(256) void k_buildV(const int* __restrict__ topk,
                                                int* __restrict__ L,
                                                int* __restrict__ cnt) {
  int tid = threadIdx.x;
  int grp = tid >> 4, gl = tid & 15;
  int i = blockIdx.x * 16 + grp;
  bool act = (gl < TOPK);
  int j = act ? topk[i * TOPK + gl] : 0;
  bool mut = false;
  if (act) {
#pragma unroll
    for (int q = 0; q < TOPK; ++q) mut |= (topk[j * TOPK + q] == i);
  }
  unsigned long long m = __ballot(mut);
  int base = tid & 48;                           // 16-lane group base within wave
  unsigned gm = (unsigned)((m >> base) & 0xFFFFull);
  int pos = __popc(gm & ((1u << gl) - 1));       // rank-order preserved
  if (mut) L[i * TOPK + pos] = j;
  if (gl == 0) cnt[i] = __popc(gm);
}

// ---------------- sparse W_C loss: one 16-lane group per task, sd from Gsd ----------------
__global__ __launch_bounds__(256) void k_wc(const int* __restrict__ topk,
                                            const int* __restrict__ L,
                                            const int* __restrict__ cnt,
                                            const f16* __restrict__ Gsd,
                                            const float* __restrict__ rowsum,
                                            double* __restrict__ pw) {
  __shared__ double red[16];
  int tid = threadIdx.x;
  int grp = tid >> 4;
  int gl = tid & 15;
  int task = blockIdx.x * 16 + grp;
  int i = task / TOPK_HALF, m = task % TOPK_HALF;
  int r = topk[i * TOPK + m];
  int cr = cnt[r];
  float invmi = 1.0f / (rowsum[i] * INV_N);
  int lval = (gl < cr) ? L[r * TOPK + gl] : -1;
  int Lr[TOPK];
#pragma unroll
  for (int a = 0; a < TOPK; ++a) Lr[a] = __shfl(lval, a, 16);
  float contrib = 0.f;
  if (gl < cr) {
    int j = lval;
    if (j != i) {
      int cj = cnt[j];
      float mj = rowsum[j] * INV_N;
      float sr_ = f16tof(((const u16*)Gsd)[(size_t)i * N + j]);
      int lj[TOPK];
#pragma unroll
      for (int b = 0; b < TOPK; ++b) lj[b] = L[j * TOPK + b];
      int vv = 0;
#pragma unroll
      for (int b = 0; b < TOPK; ++b) {
        if (b < cj) {
#pragma unroll
          for (int a = 0; a < TOPK; ++a)
            vv += ((a < cr) && (lj[b] == Lr[a])) ? 1 : 0;
        }
      }
      float denom = (float)(cr > 1 ? cr : 1);
      float wgt = (float)vv / denom;
      float sdij = sr_ * invmi;
      float sdji = sr_ / mj;
      float Rij = fmaxf(1.0f - sdij, 0.0f); Rij *= Rij;
      float Rji = fmaxf(1.0f - sdji, 0.0f); Rji *= Rji;
      float Fij = sdij * sdij - Rij;
      float Fji = sdji * sdji - Rji;
      contrib = wgt * (Fij + Fji);
    }
  }
  double local = (double)contrib;
  local += __shfl_xor(local, 1, 16);
  local += __shfl_xor(local, 2, 16);
  local += __shfl_xor(local, 4, 16);
  local += __shfl_xor(local, 8, 16);
  if (gl == 0) red[grp] = local;
  __syncthreads();
  if (tid == 0) {
    double s = 0.0;
#pragma unroll
    for (int g = 0; g < 16; ++g) s += red[g];
    pw[blockIdx.x] = s * (1.0 / 20.0);
  }
}

// ---------------- final reduce ----------------
__global__ __launch_bounds__(256) void k_final(const double* __restrict__ pd,
                                               const double* __restrict__ pw,
                                               float* __restrict__ out) {
  int tid = threadIdx.x;
  double s = 0.0;
  for (int i = tid; i < N; i += 256) s += pd[i];
  for (int i = tid; i < WC_BLOCKS; i += 256) s += pw[i];
  for (int off = 32; off > 0; off >>= 1) s += __shfl_down(s, off, 64);
  __shared__ double red[4];
  if ((tid & 63) == 0) red[tid >> 6] = s;
  __syncthreads();
  if (tid == 0)
    out[0] = (float)((red[0] + red[1] + red[2] + red[3]) /
                     ((double)N * (double)(N - 1)));
}

extern "C" void kernel_launch(void* const* d_in, const int* in_sizes, int n_in,
                              void* d_out, int out_size, void* d_ws, size_t ws_size,
                              hipStream_t stream) {
  const float* s_emb = (const float*)d_in[0];
  const float* t_emb = (const float*)d_in[1];
  const int* ids = (const int*)d_in[2];
  float* out = (float*)d_out;

  char* ws = (char*)d_ws;
  size_t off = 0;
  bf16* snorm = (bf16*)(ws + off); off += (size_t)N * D * 2;        // 4 MB
  bf16* tnorm = (bf16*)(ws + off); off += (size_t)N * D * 2;        // 4 MB
  f16*  Gsd   = (f16*)(ws + off);  off += (size_t)N * N * 2;        // 32 MB
  f16*  Gwp   = (f16*)(ws + off);  off += (size_t)N * N * 2;        // 32 MB
  float* rsq_s = (float*)(ws + off); off += (size_t)N * 4;
  float* rsq_t = (float*)(ws + off); off += (size_t)N * 4;
  float* rowsum= (float*)(ws + off); off += (size_t)N * 4;
  int*   topk  = (int*)(ws + off);   off += (size_t)N * TOPK * 4;
  int*   L     = (int*)(ws + off);   off += (size_t)N * TOPK * 4;
  int*   cnt   = (int*)(ws + off);   off += (size_t)N * 4;
  off = (off + 15) & ~(size_t)15;
  double* pd   = (double*)(ws + off); off += (size_t)N * 8;
  double* pw   = (double*)(ws + off); off += (size_t)WC_BLOCKS * 8;

  k_normalize2<<<N, 256, 0, stream>>>(s_emb, t_emb, snorm, tnorm,
                                      rsq_s, rsq_t, rowsum);
  k_dgram3<<<dim3(TRI_BLOCKS, 2), 256, 0, stream>>>(snorm, tnorm, rsq_s, rsq_t,
                                                    Gsd, Gwp, rowsum);
  k_rowpass<<<N, 256, 0, stream>>>(Gsd, Gwp, ids, rowsum, topk, pd);
  k_buildV<<<N / 16, 256, 0, stream>>>(topk, L, cnt);
  k_wc<<<WC_BLOCKS, 256, 0, stream>>>(topk, L, cnt, Gsd, rowsum, pw);
  k_final<<<1, 256, 0, stream>>>(pd, pw, out);
}

// Round 4
// 144.564 us; speedup vs baseline: 1.0654x; 1.0654x over previous
//
#include <hip/hip_runtime.h>
#include <math.h>

#define N 4096
#define D 512
#define TOPK 10
#define TOPK_HALF 5
#define NT 32
#define TRI_BLOCKS (NT * (NT + 1) / 2)   // 528
#define WC_BLOCKS (N * TOPK_HALF / 16)   // 1280: one 16-lane group per task
#define INV_N (1.0f / 4096.0f)
#define TPAD 132                          // transpose-tile pad: 2*TPAD%32==8 -> conflict-free

typedef __bf16 bf16;
typedef __bf16 bf16x4 __attribute__((ext_vector_type(4)));
typedef __bf16 bf16x8 __attribute__((ext_vector_type(8)));
typedef float f32x4 __attribute__((ext_vector_type(4)));
typedef _Float16 f16;
typedef _Float16 f16x4 __attribute__((ext_vector_type(4)));
typedef _Float16 f16x8 __attribute__((ext_vector_type(8)));
typedef unsigned short u16;
typedef unsigned short u16x8 __attribute__((ext_vector_type(8)));
typedef unsigned int u32;

__device__ __forceinline__ void gl_lds16(const void* g, void* l) {
  __builtin_amdgcn_global_load_lds(
      (const __attribute__((address_space(1))) void*)g,
      (__attribute__((address_space(3))) void*)l, 16, 0, 0);
}

__device__ __forceinline__ float f16tof(u16 h) {
  return (float)__builtin_bit_cast(_Float16, h);
}

// ---------------- K0: L2-normalize both matrices (2 rows/block, float4 loads) ----------------
__global__ __launch_bounds__(256) void k_normalize2(const float* __restrict__ xs,
                                                    const float* __restrict__ xt,
                                                    bf16* __restrict__ ys,
                                                    bf16* __restrict__ yt,
                                                    float* __restrict__ rsq_s,
                                                    float* __restrict__ rsq_t,
                                                    float* __restrict__ rowsum) {
  int b = blockIdx.x;                 // handles combined rows 2b, 2b+1 (of 8192)
  int tid = threadIdx.x;
  int half = tid >> 7;                // which row of the pair
  int l = tid & 127;                  // lane within row: 4 floats each
  int row2 = 2 * b + half;
  int is_t = row2 >> 12;
  int row = row2 & (N - 1);
  const float* x = is_t ? xt : xs;
  bf16* y = is_t ? yt : ys;
  float* rowsq = is_t ? rsq_t : rsq_s;
  const float* xr = x + (size_t)row * D;
  float4 v = *(const float4*)(xr + l * 4);
  float ss = v.x * v.x + v.y * v.y + v.z * v.z + v.w * v.w;
  __shared__ float red[4];
  __shared__ float red2[4];
  for (int off = 32; off > 0; off >>= 1) ss += __shfl_down(ss, off, 64);
  if ((tid & 63) == 0) red[tid >> 6] = ss;
  __syncthreads();
  float tot = red[half * 2] + red[half * 2 + 1];
  float inv = 1.0f / fmaxf(sqrtf(tot), 1e-12f);
  bf16x4 bv;
  bv[0] = (bf16)(v.x * inv); bv[1] = (bf16)(v.y * inv);
  bv[2] = (bf16)(v.z * inv); bv[3] = (bf16)(v.w * inv);
  *(bf16x4*)(y + (size_t)row * D + l * 4) = bv;
  float f0 = (float)bv[0], f1 = (float)bv[1], f2 = (float)bv[2], f3 = (float)bv[3];
  float s2 = f0 * f0 + f1 * f1 + f2 * f2 + f3 * f3;
  for (int off = 32; off > 0; off >>= 1) s2 += __shfl_down(s2, off, 64);
  if ((tid & 63) == 0) red2[tid >> 6] = s2;
  __syncthreads();
  if ((tid & 127) == 0) {
    rowsq[row] = red2[half * 2] + red2[half * 2 + 1];
    if (!is_t) rowsum[row] = 0.f;
  }
}

// ---------------- Gram: depth-2 pipelined BK=32 triple-buffered K-loop (vmcnt(8)),
//                  bank-conflict-free LDS via pre-swizzled global source ----------------
// Panel = 128 rows x 64 B (4 chunks of 16B). Stored chunk k of row r holds global
// chunk k ^ ((r>>1)&3); reads XOR the same value. ds_read_b128 bank-base
// (4r + quad^((r>>1)&3)) mod 8 covers all 8 values -> minimal 8-lanes/base (free).
__global__ __launch_bounds__(256) void k_dgram3(const bf16* __restrict__ S,
                                                const bf16* __restrict__ T,
                                                const float* __restrict__ rsq_s,
                                                const float* __restrict__ rsq_t,
                                                f16* __restrict__ Gsd,
                                                f16* __restrict__ Gwp,
                                                float* __restrict__ rowsum) {
  __shared__ __align__(16) char sm[49152];  // 3x16KB staging / [128][TPAD] f16 transpose union
  f16* tp = (f16*)sm;

  int z = blockIdx.y;
  const bf16* Y = z ? T : S;
  const float* rsq = z ? rsq_t : rsq_s;
  f16* G = z ? Gwp : Gsd;

  // XCD-chunked swizzle (bijective: 528 % 8 == 0)
  int orig = blockIdx.x;
  int t = (orig & 7) * (TRI_BLOCKS / 8) + (orig >> 3);
  int by = 0;
  while (t >= NT - by) { t -= NT - by; ++by; }
  int bx = by + t;
  bool offdiag = (bx != by);

  int tid = threadIdx.x;
  int lane = tid & 63, w = tid >> 6;
  int wr = w >> 1, wc = w & 1;
  int quad = lane >> 4, c = lane & 15;
  int w1024 = w << 10;

  const char* Jbase = (const char*)(Y + (size_t)(bx * 128) * D);
  const char* Ibase = (const char*)(Y + (size_t)(by * 128) * D);

  // staging: slot s = tid (rows 0..63) and s = tid+256 (rows 64..127), 16B each
  int r0 = tid >> 2;
  int cs0 = (tid & 3) ^ ((tid >> 3) & 3);           // swizzled global chunk
  int goff0 = r0 * (D * 2) + cs0 * 16;
  int goff1 = goff0 + 64 * (D * 2);                 // +64 rows, same chunk xor

  int jrow = wr * 64 + c;
  int irow = wc * 64 + c;
  int jx16 = (quad ^ ((jrow >> 1) & 3)) << 4;       // read-side chunk offset (bytes)
  int ix16 = (quad ^ ((irow >> 1) & 3)) << 4;

#define STAGE(buf, kb)                                   \
  {                                                      \
    char* _b = (buf);                                    \
    gl_lds16(Jbase + goff0 + (kb), _b + w1024);          \
    gl_lds16(Jbase + goff1 + (kb), _b + 4096 + w1024);   \
    gl_lds16(Ibase + goff0 + (kb), _b + 8192 + w1024);   \
    gl_lds16(Ibase + goff1 + (kb), _b + 12288 + w1024);  \
  }

#define COMPUTE(bufc)                                                          \
  {                                                                            \
    const char* Jc = (const char*)(bufc);                                      \
    const char* Ic = (const char*)(bufc) + 8192;                               \
    bf16x8 af[4], bfr[4];                                                      \
    _Pragma("unroll") for (int u = 0; u < 4; ++u)                              \
        af[u] = *(const bf16x8*)(Jc + (jrow + u * 16) * 64 + jx16);            \
    _Pragma("unroll") for (int v = 0; v < 4; ++v)                              \
        bfr[v] = *(const bf16x8*)(Ic + (irow + v * 16) * 64 + ix16);           \
    _Pragma("unroll") for (int u = 0; u < 4; ++u)                              \
      _Pragma("unroll") for (int v = 0; v < 4; ++v)                            \
        acc[u][v] = __builtin_amdgcn_mfma_f32_16x16x32_bf16(                   \
            af[u], bfr[v], acc[u][v], 0, 0, 0);                                \
  }

  f32x4 acc[4][4] = {};
  // prologue: steps 0 and 1 in flight
  STAGE(sm, 0);
  STAGE(sm + 16384, 64);
  int sc = 0, sn = 2;                    // slot of current step / of step t+2
  for (int tt = 0; tt < 14; ++tt) {
    char* nb = sm + (sn << 14);
    // all waves finished compute(tt-1) (which used slot sn) -> safe to overwrite
    asm volatile("s_barrier" ::: "memory");
    STAGE(nb, (size_t)(tt + 2) * 64);
    // counted wait: 8 loads (steps tt+1, tt+2) stay in flight; step-tt loads done
    asm volatile("s_waitcnt vmcnt(8)\n\ts_barrier" ::: "memory");
    COMPUTE(sm + (sc << 14));
    // own-wave ds_reads complete before the next barrier opens the slot (rule #18)
    asm volatile("s_waitcnt lgkmcnt(0)" ::: "memory");
    sc = (sc == 2) ? 0 : sc + 1;
    sn = (sn == 2) ? 0 : sn + 1;
  }
  // peeled steps 14 (slot 2) and 15 (slot 0)
  asm volatile("s_waitcnt vmcnt(4)\n\ts_barrier" ::: "memory");
  COMPUTE(sm + 32768);
  asm volatile("s_waitcnt vmcnt(0) lgkmcnt(0)\n\ts_barrier" ::: "memory");
  COMPUTE(sm);
  __syncthreads();                       // staging buffers dead; tp union safe

#undef STAGE
#undef COMPUTE

  // direct store G[i][j] (+ transpose-tile write for off-diag)
#pragma unroll
  for (int v = 0; v < 4; ++v) {
    int il = wc * 64 + v * 16 + c;
    int ig = by * 128 + il;
    float ri = rsq[ig];
    float rsv = 0.f;
#pragma unroll
    for (int u = 0; u < 4; ++u) {
      int jl0 = wr * 64 + u * 16 + quad * 4;
      int jb0i = bx * 128 + jl0;
      float4 rj = *(const float4*)(rsq + jb0i);
      const float* rjp = (const float*)&rj;
      f32x4 a = acc[u][v];
      f16x4 st;
      if (z == 0) {
#pragma unroll
        for (int reg = 0; reg < 4; ++reg) {
          float sq = fmaxf(ri + rjp[reg] - 2.0f * a[reg], 0.0f);
          float val = __builtin_amdgcn_sqrtf(sq);   // 1 x v_sqrt_f32; f16-stored
          st[reg] = (_Float16)val;
          rsv += val;
        }
      } else {
#pragma unroll
        for (int reg = 0; reg < 4; ++reg) {
          float sq = fmaxf(ri + rjp[reg] - 2.0f * a[reg], 0.0f);
          st[reg] = (_Float16)__expf(-sq);          // v_exp-based; f16-stored
        }
      }
      *(f16x4*)(G + (size_t)ig * N + jb0i) = st;
      if (offdiag) {
#pragma unroll
        for (int reg = 0; reg < 4; ++reg) tp[(jl0 + reg) * TPAD + il] = st[reg];
      }
    }
    if (z == 0) {
      rsv += __shfl_xor(rsv, 16, 64);
      rsv += __shfl_xor(rsv, 32, 64);
      if (lane < 16) atomicAdd(&rowsum[ig], rsv);
    }
  }

  // mirrored store G[j][i]: 16 lanes/row, 256 B contiguous -> full-line writes
  if (offdiag) {
    __syncthreads();
    int rloc = tid >> 4;
    int cseg = tid & 15;
#pragma unroll
    for (int it = 0; it < 8; ++it) {
      int jl = it * 16 + rloc;
      int jg = bx * 128 + jl;
      f16x8 v8 = *(f16x8*)&tp[jl * TPAD + cseg * 8];
      *(f16x8*)(G + (size_t)jg * N + by * 128 + cseg * 8) = v8;
      if (z == 0) {
        float csum = 0.f;
#pragma unroll
        for (int e = 0; e < 8; ++e) csum += (float)v8[e];
        csum += __shfl_xor(csum, 1, 64);
        csum += __shfl_xor(csum, 2, 64);
        csum += __shfl_xor(csum, 4, 64);
        csum += __shfl_xor(csum, 8, 64);
        if (cseg == 0) atomicAdd(&rowsum[jg], csum);
      }
    }
  }
}

// ---------------- Row pass: bitonic top-10 + dense loss; register merge-path tree ----------------
__global__ __launch_bounds__(256) void k_rowpass(const f16* __restrict__ Gs,
                                                 const f16* __restrict__ Gw,
                                                 const int* __restrict__ ids,
                                                 const float* __restrict__ rowsum,
                                                 int* __restrict__ topk,
                                                 double* __restrict__ pd) {
  __shared__ u32 lds[256 * TOPK];  // 10 KB
  __shared__ double dred[4];
  int i = blockIdx.x, tid = threadIdx.x;
  int idi = ids[i];
  float invm = 1.0f / (rowsum[i] * INV_N);
  const u16* srow = (const u16*)(Gs + (size_t)i * N);
  const u16* wrow = (const u16*)(Gw + (size_t)i * N);
  u32 key[16];
  float dsum = 0.f;
  int j0 = tid * 16;
#pragma unroll
  for (int h = 0; h < 2; ++h) {
    int jb = j0 + h * 8;
    u16x8 sv = *(const u16x8*)(srow + jb);
    u16x8 wv = *(const u16x8*)(wrow + jb);
    int4 id0 = *(const int4*)(ids + jb);
    int4 id1 = *(const int4*)(ids + jb + 4);
    const int* idp = (const int*)&id0;
    const int* idp1 = (const int*)&id1;
#pragma unroll
    for (int e = 0; e < 8; ++e) {
      int j = jb + e;
      u16 hw = wv[e];
      float wp = f16tof(hw);
      if (j != i) {
        float sdn = f16tof(sv[e]) * invm;
        float r = fmaxf(1.0f - sdn, 0.0f); r *= r;
        dsum += r + 0.5f * wp * (sdn * sdn - r);
      }
      int idj = (e < 4) ? idp[e] : idp1[e - 4];
      u16 hk = (idj == idi) ? (u16)0x3C00 : hw;
      key[h * 8 + e] = ((u32)hk << 16) | (u32)(4095 - j);
    }
  }
  // bitonic sort-16 descending (branch-free)
#pragma unroll
  for (int kk = 2; kk <= 16; kk <<= 1) {
#pragma unroll
    for (int jj = kk >> 1; jj > 0; jj >>= 1) {
#pragma unroll
      for (int ii = 0; ii < 16; ++ii) {
        int ll = ii ^ jj;
        if (ll > ii) {
          bool desc = ((ii & kk) == 0);
          u32 a = key[ii], b = key[ll];
          bool sw = desc ? (a < b) : (a > b);
          key[ii] = sw ? b : a;
          key[ll] = sw ? a : b;
        }
      }
    }
  }
  double dl = (double)dsum;
  for (int off = 32; off > 0; off >>= 1) dl += __shfl_down(dl, off, 64);
  if ((tid & 63) == 0) dred[tid >> 6] = dl;
#pragma unroll
  for (int o = 0; o < TOPK; ++o) lds[tid * TOPK + o] = key[o];
  __syncthreads();
  // merge tree: load both lists, merge-path in registers (no dependent LDS chains)
  for (int off = 128; off >= 1; off >>= 1) {
    if (tid < off) {
      u32 A[TOPK], B[TOPK];
#pragma unroll
      for (int o = 0; o < TOPK; ++o) {
        A[o] = lds[tid * TOPK + o];
        B[o] = lds[(tid + off) * TOPK + o];
      }
      u32 out[TOPK];
#pragma unroll
      for (int o = 0; o < TOPK; ++o) {
        u32 m = A[o] > B[o] ? A[o] : B[o];
#pragma unroll
        for (int p = 0; p < o; ++p) {
          u32 mn = A[p] < B[o - 1 - p] ? A[p] : B[o - 1 - p];
          m = m > mn ? m : mn;
        }
        out[o] = m;
      }
#pragma unroll
      for (int o = 0; o < TOPK; ++o) lds[tid * TOPK + o] = out[o];
    }
    __syncthreads();
  }
  if (tid == 0) {
#pragma unroll
    for (int o = 0; o < TOPK; ++o)
      topk[i * TOPK + o] = 4095 - (int)(lds[o] & 0xFFFu);
    pd[i] = dred[0] + dred[1] + dred[2] + dred[3];
  }
}

// ---------------- mutual-kNN lists: one 16-lane group per row, ballot-compaction ----------------
__global__ __launch_bounds__(256) void k_buildV(const int* __restrict__ topk,
                                                int* __restrict__ L,
                                                int* __restrict__ cnt) {
  int tid = threadIdx.x;
  int grp = tid >> 4, gl = tid & 15;
  int i = blockIdx.x * 16 + grp;
  bool act = (gl < TOPK);
  int j = act ? topk[i * TOPK + gl] : 0;
  bool mut = false;
  if (act) {
#pragma unroll
    for (int q = 0; q < TOPK; ++q) mut |= (topk[j * TOPK + q] == i);
  }
  unsigned long long m = __ballot(mut);
  int base = tid & 48;                           // 16-lane group base within wave
  unsigned gm = (unsigned)((m >> base) & 0xFFFFull);
  int pos = __popc(gm & ((1u << gl) - 1));       // rank-order preserved
  if (mut) L[i * TOPK + pos] = j;
  if (gl == 0) cnt[i] = __popc(gm);
}

// ---------------- sparse W_C loss: one 16-lane group per task, sd from Gsd ----------------
__global__ __launch_bounds__(256) void k_wc(const int* __restrict__ topk,
                                            const int* __restrict__ L,
                                            const int* __restrict__ cnt,
                                            const f16* __restrict__ Gsd,
                                            const float* __restrict__ rowsum,
                                            double* __restrict__ pw) {
  __shared__ double red[16];
  int tid = threadIdx.x;
  int grp = tid >> 4;
  int gl = tid & 15;
  int task = blockIdx.x * 16 + grp;
  int i = task / TOPK_HALF, m = task % TOPK_HALF;
  int r = topk[i * TOPK + m];
  int cr = cnt[r];
  float invmi = 1.0f / (rowsum[i] * INV_N);
  int lval = (gl < cr) ? L[r * TOPK + gl] : -1;
  int Lr[TOPK];
#pragma unroll
  for (int a = 0; a < TOPK; ++a) Lr[a] = __shfl(lval, a, 16);
  float contrib = 0.f;
  if (gl < cr) {
    int j = lval;
    if (j != i) {
      int cj = cnt[j];
      float mj = rowsum[j] * INV_N;
      float sr_ = f16tof(((const u16*)Gsd)[(size_t)i * N + j]);
      int lj[TOPK];
#pragma unroll
      for (int b = 0; b < TOPK; ++b) lj[b] = L[j * TOPK + b];
      int vv = 0;
#pragma unroll
      for (int b = 0; b < TOPK; ++b) {
        if (b < cj) {
#pragma unroll
          for (int a = 0; a < TOPK; ++a)
            vv += ((a < cr) && (lj[b] == Lr[a])) ? 1 : 0;
        }
      }
      float denom = (float)(cr > 1 ? cr : 1);
      float wgt = (float)vv / denom;
      float sdij = sr_ * invmi;
      float sdji = sr_ / mj;
      float Rij = fmaxf(1.0f - sdij, 0.0f); Rij *= Rij;
      float Rji = fmaxf(1.0f - sdji, 0.0f); Rji *= Rji;
      float Fij = sdij * sdij - Rij;
      float Fji = sdji * sdji - Rji;
      contrib = wgt * (Fij + Fji);
    }
  }
  double local = (double)contrib;
  local += __shfl_xor(local, 1, 16);
  local += __shfl_xor(local, 2, 16);
  local += __shfl_xor(local, 4, 16);
  local += __shfl_xor(local, 8, 16);
  if (gl == 0) red[grp] = local;
  __syncthreads();
  if (tid == 0) {
    double s = 0.0;
#pragma unroll
    for (int g = 0; g < 16; ++g) s += red[g];
    pw[blockIdx.x] = s * (1.0 / 20.0);
  }
}

// ---------------- final reduce ----------------
__global__ __launch_bounds__(256) void k_final(const double* __restrict__ pd,
                                               const double* __restrict__ pw,
                                               float* __restrict__ out) {
  int tid = threadIdx.x;
  double s = 0.0;
  for (int i = tid; i < N; i += 256) s += pd[i];
  for (int i = tid; i < WC_BLOCKS; i += 256) s += pw[i];
  for (int off = 32; off > 0; off >>= 1) s += __shfl_down(s, off, 64);
  __shared__ double red[4];
  if ((tid & 63) == 0) red[tid >> 6] = s;
  __syncthreads();
  if (tid == 0)
    out[0] = (float)((red[0] + red[1] + red[2] + red[3]) /
                     ((double)N * (double)(N - 1)));
}

extern "C" void kernel_launch(void* const* d_in, const int* in_sizes, int n_in,
                              void* d_out, int out_size, void* d_ws, size_t ws_size,
                              hipStream_t stream) {
  const float* s_emb = (const float*)d_in[0];
  const float* t_emb = (const float*)d_in[1];
  const int* ids = (const int*)d_in[2];
  float* out = (float*)d_out;

  char* ws = (char*)d_ws;
  size_t off = 0;
  bf16* snorm = (bf16*)(ws + off); off += (size_t)N * D * 2;        // 4 MB
  bf16* tnorm = (bf16*)(ws + off); off += (size_t)N * D * 2;        // 4 MB
  f16*  Gsd   = (f16*)(ws + off);  off += (size_t)N * N * 2;        // 32 MB
  f16*  Gwp   = (f16*)(ws + off);  off += (size_t)N * N * 2;        // 32 MB
  float* rsq_s = (float*)(ws + off); off += (size_t)N * 4;
  float* rsq_t = (float*)(ws + off); off += (size_t)N * 4;
  float* rowsum= (float*)(ws + off); off += (size_t)N * 4;
  int*   topk  = (int*)(ws + off);   off += (size_t)N * TOPK * 4;
  int*   L     = (int*)(ws + off);   off += (size_t)N * TOPK * 4;
  int*   cnt   = (int*)(ws + off);   off += (size_t)N * 4;
  off = (off + 15) & ~(size_t)15;
  double* pd   = (double*)(ws + off); off += (size_t)N * 8;
  double* pw   = (double*)(ws + off); off += (size_t)WC_BLOCKS * 8;

  k_normalize2<<<N, 256, 0, stream>>>(s_emb, t_emb, snorm, tnorm,
                                      rsq_s, rsq_t, rowsum);
  k_dgram3<<<dim3(TRI_BLOCKS, 2), 256, 0, stream>>>(snorm, tnorm, rsq_s, rsq_t,
                                                    Gsd, Gwp, rowsum);
  k_rowpass<<<N, 256, 0, stream>>>(Gsd, Gwp, ids, rowsum, topk, pd);
  k_buildV<<<N / 16, 256, 0, stream>>>(topk, L, cnt);
  k_wc<<<WC_BLOCKS, 256, 0, stream>>>(topk, L, cnt, Gsd, rowsum, pw);
  k_final<<<1, 256, 0, stream>>>(pd, pw, out);
}